// Round 1
// baseline (1291.163 us; speedup 1.0000x reference)
//
#include <hip/hip_runtime.h>
#include <cmath>

// Problem constants
#define D_MODEL 1024
#define KOSC    256
#define NSEQ    4096
#define BATCH   4
#define NROW    (BATCH * NSEQ)   // 16384 rows (b*n)
#define JTOT    1792             // 6K proj + K phase

// SGEMM tiling
#define TM 128
#define TN 128
#define TK 8
#define LDSP (TM + 4)

__device__ __forceinline__ float sigm(float x) {
    return 1.0f / (1.0f + expf(-x));
}
__device__ __forceinline__ float softplusf_(float x) {
    return fmaxf(x, 0.0f) + log1pf(expf(-fabsf(x)));
}

// ---------------------------------------------------------------------------
// Pack W_res (1024 x 1022) into padded WP (1024 x 1024), zeros in cols 1022-23
// ---------------------------------------------------------------------------
__global__ __launch_bounds__(256) void pack_wres_kernel(
    const float* __restrict__ Wres, float* __restrict__ WP)
{
    int idx = blockIdx.x * 256 + threadIdx.x;     // 0 .. 1024*1024-1
    int d = idx >> 10;
    int j = idx & 1023;
    WP[idx] = (j < 1022) ? Wres[(size_t)d * 1022 + j] : 0.0f;
}

// ---------------------------------------------------------------------------
// GEMM1: PT[j, r] = sum_d Wcat[j,d] * x[r,d] + bcat[j]
//   M = JTOT = 1792 (j), N = NROW = 16384 (r), K = 1024
//   PT row-major (j, r) -> r contiguous (so the scan kernel reads channels
//   as contiguous rows)
// ---------------------------------------------------------------------------
__global__ __launch_bounds__(256, 2) void gemm_proj_kernel(
    const float* __restrict__ x,
    const float* __restrict__ Wproj, const float* __restrict__ bproj,
    const float* __restrict__ Wphase, const float* __restrict__ bphase,
    float* __restrict__ PT)
{
    __shared__ float As[TK][LDSP];   // As[d][j_local]
    __shared__ float Bs[TK][LDSP];   // Bs[d][r_local]
    const int tid = threadIdx.x;
    const int j0 = blockIdx.y * TM;
    const int r0 = blockIdx.x * TN;

    const int lrow = tid >> 1;            // 0..127
    const int lcol = (tid & 1) << 2;      // 0 or 4

    const int jj = j0 + lrow;
    const float* Asrc = (jj < 1536) ? (Wproj + (size_t)jj * D_MODEL)
                                    : (Wphase + (size_t)(jj - 1536) * D_MODEL);
    const float* Bsrc = x + (size_t)(r0 + lrow) * D_MODEL;

    const int tx = tid & 15;   // r fragment
    const int ty = tid >> 4;   // j fragment

    float acc[8][8];
    #pragma unroll
    for (int i = 0; i < 8; i++)
        #pragma unroll
        for (int j = 0; j < 8; j++) acc[i][j] = 0.0f;

    for (int k0 = 0; k0 < D_MODEL; k0 += TK) {
        float4 av = *(const float4*)(Asrc + k0 + lcol);
        float4 bv = *(const float4*)(Bsrc + k0 + lcol);
        __syncthreads();
        As[lcol+0][lrow] = av.x; As[lcol+1][lrow] = av.y;
        As[lcol+2][lrow] = av.z; As[lcol+3][lrow] = av.w;
        Bs[lcol+0][lrow] = bv.x; Bs[lcol+1][lrow] = bv.y;
        Bs[lcol+2][lrow] = bv.z; Bs[lcol+3][lrow] = bv.w;
        __syncthreads();
        #pragma unroll
        for (int kk = 0; kk < TK; kk++) {
            float4 a0 = *(const float4*)&As[kk][ty * 4];
            float4 a1 = *(const float4*)&As[kk][ty * 4 + 64];
            float4 b0 = *(const float4*)&Bs[kk][tx * 4];
            float4 b1 = *(const float4*)&Bs[kk][tx * 4 + 64];
            float af[8] = {a0.x,a0.y,a0.z,a0.w,a1.x,a1.y,a1.z,a1.w};
            float bf[8] = {b0.x,b0.y,b0.z,b0.w,b1.x,b1.y,b1.z,b1.w};
            #pragma unroll
            for (int i = 0; i < 8; i++)
                #pragma unroll
                for (int j = 0; j < 8; j++)
                    acc[i][j] = fmaf(af[i], bf[j], acc[i][j]);
        }
    }

    #pragma unroll
    for (int i = 0; i < 8; i++) {
        int j = j0 + ((i < 4) ? (ty * 4 + i) : (64 + ty * 4 + (i - 4)));
        float bb = (j < 1536) ? bproj[j] : bphase[j - 1536];
        float* dst = PT + (size_t)j * NROW + r0;
        float4 v0 = {acc[i][0]+bb, acc[i][1]+bb, acc[i][2]+bb, acc[i][3]+bb};
        float4 v1 = {acc[i][4]+bb, acc[i][5]+bb, acc[i][6]+bb, acc[i][7]+bb};
        *(float4*)(dst + tx * 4)      = v0;
        *(float4*)(dst + 64 + tx * 4) = v1;
    }
}

// ---------------------------------------------------------------------------
// Scan kernel: one block per (b, k) channel. Does activations, linear
// recurrence (block-parallel prefix scan), erase, normalize, demodulate,
// phase gate. Overwrites its own (already-consumed) PT rows in place:
//   row k      <- rho_re (gated)
//   row 256+k  <- rho_im (gated)
//   row 512+k  <- g
//   row 768+k  <- g*rho_re   (= RT row k)
//   row 1024+k <- g*rho_im   (= RT row 256+k)
// ---------------------------------------------------------------------------
__global__ __launch_bounds__(256) void scan_kernel(float* PT,
                                                   const float* lambda_ptr)
{
    const int bx = blockIdx.x;         // 0..1023
    const int k = bx & 255;
    const int b = bx >> 8;
    const int t = threadIdx.x;         // 0..255
    const size_t colb = (size_t)b * NSEQ;
    const size_t R = NROW;

    float* rowA  = PT + (size_t)(k)        * R + colb;  // a_raw
    float* rowW  = PT + (size_t)(256 + k)  * R + colb;  // w_raw
    float* rowP  = PT + (size_t)(512 + k)  * R + colb;  // p_raw
    float* rowAl = PT + (size_t)(768 + k)  * R + colb;  // al_raw
    float* rowG  = PT + (size_t)(1024 + k) * R + colb;  // g_raw
    float* rowBe = PT + (size_t)(1280 + k) * R + colb;  // be_raw
    float* rowPq = PT + (size_t)(1536 + k) * R + colb;  // phase query

    __shared__ float s_al[NSEQ + 256];
    __shared__ float s_rr[NSEQ + 256];
    __shared__ float s_ri[NSEQ + 256];
    __shared__ float s_sa[256], s_sbr[256], s_sbi[256];

    const float lam = *lambda_ptr;

    // phase 1: activations + drive, coalesced global reads -> LDS
    for (int i = 0; i < 16; i++) {
        int n = i * 256 + t;
        float araw = rowA[n];
        float wraw = rowW[n];
        float praw = rowP[n];
        float alraw = rowAl[n];
        float A     = 3.0f * sigm(araw);
        float alpha = sigm(alraw);
        float omega = softplusf_(wraw);
        float pos   = log1pf((float)n);
        float ang   = fmaf(omega, pos, praw);
        float sn, cs;
        sincosf(ang, &sn, &cs);
        float amp = (1.0f - alpha) * A;
        int pidx = n + (n >> 4);
        s_al[pidx] = alpha;
        s_rr[pidx] = amp * cs;   // drive_r
        s_ri[pidx] = amp * sn;   // drive_i
    }
    __syncthreads();

    // phase 2a: thread-local summary over n = t*16 .. t*16+15
    {
        float ap = 1.0f, br = 0.0f, bi = 0.0f;
        int base = t * 17;   // padded base for n = t*16
        #pragma unroll
        for (int i = 0; i < 16; i++) {
            float a = s_al[base + i];
            br = fmaf(a, br, s_rr[base + i]);
            bi = fmaf(a, bi, s_ri[base + i]);
            ap *= a;
        }
        s_sa[t] = ap; s_sbr[t] = br; s_sbi[t] = bi;
    }
    __syncthreads();

    // phase 2b: Hillis-Steele inclusive scan over 256 thread summaries
    for (int off = 1; off < 256; off <<= 1) {
        float a2 = s_sa[t], b2r = s_sbr[t], b2i = s_sbi[t];
        float a1 = 1.0f, b1r = 0.0f, b1i = 0.0f;
        if (t >= off) { a1 = s_sa[t - off]; b1r = s_sbr[t - off]; b1i = s_sbi[t - off]; }
        __syncthreads();
        s_sa[t]  = a1 * a2;
        s_sbr[t] = fmaf(a2, b1r, b2r);
        s_sbi[t] = fmaf(a2, b1i, b2i);
        __syncthreads();
    }

    // phase 2c: re-scan locally with exclusive carry, store r into s_rr/s_ri
    {
        float cr = 0.0f, ci = 0.0f;
        if (t > 0) { cr = s_sbr[t - 1]; ci = s_sbi[t - 1]; }
        int base = t * 17;
        #pragma unroll
        for (int i = 0; i < 16; i++) {
            float a = s_al[base + i];
            cr = fmaf(a, cr, s_rr[base + i]);
            ci = fmaf(a, ci, s_ri[base + i]);
            s_rr[base + i] = cr;
            s_ri[base + i] = ci;
        }
    }
    __syncthreads();

    // phase 3: erase, normalize, demodulate, phase-gate; write outputs
    for (int i = 0; i < 16; i++) {
        int n = i * 256 + t;
        float wraw = rowW[n];
        float praw = rowP[n];
        float beraw = rowBe[n];
        float graw = rowG[n];
        float pq = rowPq[n];

        float omega = softplusf_(wraw);
        float ang = fmaf(omega, log1pf((float)n), praw);
        float sn, cs;
        sincosf(ang, &sn, &cs);

        int pidx = n + (n >> 4);
        float rr = s_rr[pidx], ri = s_ri[pidx];
        float beta = sigm(beraw);
        float g = sigm(graw);

        float readout = rr * cs + ri * sn;
        rr -= beta * readout * cs;
        ri -= beta * readout * sn;

        float modulus = sqrtf(rr * rr + ri * ri + 1e-8f);
        float scale = fmaxf(modulus, 1.0f);
        rr /= scale; ri /= scale;

        float rho_re = rr * cs + ri * sn;
        float rho_im = -rr * sn + ri * cs;

        float rho_norm = sqrtf(rho_re * rho_re + rho_im * rho_im + 1e-8f);
        float sq, cq;
        sincosf(pq, &sq, &cq);
        float pa = (rho_re * cq + rho_im * sq) / rho_norm;
        float gate = sigm(lam * pa);
        rho_re *= gate;
        rho_im *= gate;

        rowA[n]  = rho_re;        // ungated-by-g rho for cross products
        rowW[n]  = rho_im;
        rowP[n]  = g;
        rowAl[n] = g * rho_re;    // RT row k
        rowG[n]  = g * rho_im;    // RT row 256+k
    }
}

// ---------------------------------------------------------------------------
// Cross kernel: neighbor complex cross products, writes RT rows 512..1021
// and zeros pad rows 1022-1023.  RT row j == PT row 768+j.
// ---------------------------------------------------------------------------
__global__ __launch_bounds__(256) void cross_kernel(float* PT)
{
    int k = blockIdx.y;                       // 0..256
    int col = blockIdx.x * 256 + threadIdx.x; // 0..16383
    float* RT = PT + (size_t)768 * NROW;
    if (k == 255) { RT[(size_t)1022 * NROW + col] = 0.0f; return; }
    if (k == 256) { RT[(size_t)1023 * NROW + col] = 0.0f; return; }

    float re0 = PT[(size_t)(k)       * NROW + col];
    float re1 = PT[(size_t)(k + 1)   * NROW + col];
    float im0 = PT[(size_t)(256 + k) * NROW + col];
    float im1 = PT[(size_t)(257 + k) * NROW + col];
    float g0  = PT[(size_t)(512 + k) * NROW + col];
    float g1  = PT[(size_t)(513 + k) * NROW + col];
    float gc = 0.5f * (g0 + g1);
    RT[(size_t)(512 + k) * NROW + col] = gc * (re0 * re1 - im0 * im1);
    RT[(size_t)(767 + k) * NROW + col] = gc * (re0 * im1 + im0 * re1);
}

// ---------------------------------------------------------------------------
// GEMM2: out[r, d] = rs * sum_j RT[j, r] * WP[d, j]
//   M = 16384 (r), N = 1024 (d), K = 1024 (j, padded from 1022)
// ---------------------------------------------------------------------------
__global__ __launch_bounds__(256, 2) void gemm_out_kernel(
    const float* __restrict__ RT,   // (1024 x 16384), j-major
    const float* __restrict__ WP,   // (1024 x 1024) padded W_res
    const float* __restrict__ rs_ptr,
    float* __restrict__ out)        // (16384 x 1024)
{
    __shared__ float As[TK][LDSP];  // As[j][r_local]
    __shared__ float Bs[TK][LDSP];  // Bs[j][d_local]
    const int tid = threadIdx.x;
    const int m0 = blockIdx.y * TM;   // r tile
    const int n0 = blockIdx.x * TN;   // d tile
    const float rs = *rs_ptr;

    const int a_j = tid >> 5;            // 0..7
    const int a_r = (tid & 31) << 2;     // 0..124
    const int b_d = tid >> 1;            // 0..127
    const int b_j = (tid & 1) << 2;      // 0 or 4

    const int tx = tid & 15;   // d fragment
    const int ty = tid >> 4;   // r fragment

    float acc[8][8];
    #pragma unroll
    for (int i = 0; i < 8; i++)
        #pragma unroll
        for (int j = 0; j < 8; j++) acc[i][j] = 0.0f;

    const float* Bsrc = WP + (size_t)(n0 + b_d) * 1024;

    for (int k0 = 0; k0 < 1024; k0 += TK) {
        float4 av = *(const float4*)(RT + (size_t)(k0 + a_j) * NROW + m0 + a_r);
        float4 bv = *(const float4*)(Bsrc + k0 + b_j);
        __syncthreads();
        *(float4*)&As[a_j][a_r] = av;
        Bs[b_j+0][b_d] = bv.x; Bs[b_j+1][b_d] = bv.y;
        Bs[b_j+2][b_d] = bv.z; Bs[b_j+3][b_d] = bv.w;
        __syncthreads();
        #pragma unroll
        for (int kk = 0; kk < TK; kk++) {
            float4 a0 = *(const float4*)&As[kk][ty * 4];
            float4 a1 = *(const float4*)&As[kk][ty * 4 + 64];
            float4 b0 = *(const float4*)&Bs[kk][tx * 4];
            float4 b1 = *(const float4*)&Bs[kk][tx * 4 + 64];
            float af[8] = {a0.x,a0.y,a0.z,a0.w,a1.x,a1.y,a1.z,a1.w};
            float bf[8] = {b0.x,b0.y,b0.z,b0.w,b1.x,b1.y,b1.z,b1.w};
            #pragma unroll
            for (int i = 0; i < 8; i++)
                #pragma unroll
                for (int j = 0; j < 8; j++)
                    acc[i][j] = fmaf(af[i], bf[j], acc[i][j]);
        }
    }

    #pragma unroll
    for (int i = 0; i < 8; i++) {
        int r = m0 + ((i < 4) ? (ty * 4 + i) : (64 + ty * 4 + (i - 4)));
        float* dst = out + (size_t)r * 1024 + n0;
        float4 v0 = {rs*acc[i][0], rs*acc[i][1], rs*acc[i][2], rs*acc[i][3]};
        float4 v1 = {rs*acc[i][4], rs*acc[i][5], rs*acc[i][6], rs*acc[i][7]};
        *(float4*)(dst + tx * 4)      = v0;
        *(float4*)(dst + 64 + tx * 4) = v1;
    }
}

// ---------------------------------------------------------------------------
extern "C" void kernel_launch(void* const* d_in, const int* in_sizes, int n_in,
                              void* d_out, int out_size, void* d_ws, size_t ws_size,
                              hipStream_t stream)
{
    const float* x      = (const float*)d_in[0];
    const float* Wproj  = (const float*)d_in[1];
    const float* bproj  = (const float*)d_in[2];
    const float* Wres   = (const float*)d_in[3];
    const float* Wphase = (const float*)d_in[4];
    const float* bphase = (const float*)d_in[5];
    const float* lam    = (const float*)d_in[6];
    const float* rs     = (const float*)d_in[7];
    float* out = (float*)d_out;

    float* PT = (float*)d_ws;                                   // 1792 x 16384
    float* WP = (float*)((char*)d_ws + (size_t)JTOT * NROW * 4); // 1024 x 1024
    float* RT = PT + (size_t)768 * NROW;                        // aliases PT rows 768..1791

    hipLaunchKernelGGL(pack_wres_kernel, dim3(4096), dim3(256), 0, stream,
                       Wres, WP);
    hipLaunchKernelGGL(gemm_proj_kernel, dim3(NROW / TN, JTOT / TM), dim3(256), 0, stream,
                       x, Wproj, bproj, Wphase, bphase, PT);
    hipLaunchKernelGGL(scan_kernel, dim3(BATCH * KOSC), dim3(256), 0, stream,
                       PT, lam);
    hipLaunchKernelGGL(cross_kernel, dim3(NROW / 256, 257), dim3(256), 0, stream,
                       PT);
    hipLaunchKernelGGL(gemm_out_kernel, dim3(1024 / TN, NROW / TM), dim3(256), 0, stream,
                       RT, WP, rs, out);
}

// Round 2
// 639.636 us; speedup vs baseline: 2.0186x; 2.0186x over previous
//
#include <hip/hip_runtime.h>
#include <cmath>

// Problem constants
#define D_MODEL 1024
#define KOSC    256
#define NSEQ    4096
#define BATCH   4
#define NROW    (BATCH * NSEQ)   // 16384 rows (b*n)
#define JTOT    1792             // 6K proj + K phase

typedef short      s16x8 __attribute__((ext_vector_type(8)));
typedef float      f32x4 __attribute__((ext_vector_type(4)));

// async global->LDS, 16B per lane; LDS dest = wave-uniform base + lane*16
#define GL2LDS(gsrc, ldst)                                                      \
  __builtin_amdgcn_global_load_lds(                                             \
      (const __attribute__((address_space(1))) unsigned int*)(gsrc),            \
      (__attribute__((address_space(3))) unsigned int*)(ldst), 16, 0, 0)

__device__ __forceinline__ float sigm(float x) {
    return 1.0f / (1.0f + expf(-x));
}
__device__ __forceinline__ float softplusf_(float x) {
    return fmaxf(x, 0.0f) + log1pf(expf(-fabsf(x)));
}

// round-to-nearest-even bf16 split: f = hi + lo, residual ~2^-18 * |f|
__device__ __forceinline__ void bf16_split(float f, unsigned short& hi,
                                           unsigned short& lo) {
    unsigned u = __float_as_uint(f);
    unsigned r = u + 0x7FFFu + ((u >> 16) & 1u);
    hi = (unsigned short)(r >> 16);
    float fh = __uint_as_float((unsigned)hi << 16);
    float fl = f - fh;
    unsigned ul = __float_as_uint(fl);
    unsigned rl = ul + 0x7FFFu + ((ul >> 16) & 1u);
    lo = (unsigned short)(rl >> 16);
}

// ---------------------------------------------------------------------------
// split_x: x fp32 (16384x1024) -> XH, XL bf16 (in d_out scratch)
// ---------------------------------------------------------------------------
__global__ __launch_bounds__(256) void split_x_kernel(
    const float* __restrict__ x, unsigned short* __restrict__ XH,
    unsigned short* __restrict__ XL)
{
    int i = blockIdx.x * 256 + threadIdx.x;    // x4 floats
    float4 v = ((const float4*)x)[i];
    ushort4 h, l;
    bf16_split(v.x, h.x, l.x);
    bf16_split(v.y, h.y, l.y);
    bf16_split(v.z, h.z, l.z);
    bf16_split(v.w, h.w, l.w);
    ((ushort4*)XH)[i] = h;
    ((ushort4*)XL)[i] = l;
}

// ---------------------------------------------------------------------------
// split_w: [Wproj;Wphase] fp32 (1792x1024) -> WH, WL bf16
// ---------------------------------------------------------------------------
__global__ __launch_bounds__(256) void split_w_kernel(
    const float* __restrict__ Wproj, const float* __restrict__ Wphase,
    unsigned short* __restrict__ WH, unsigned short* __restrict__ WL)
{
    int i = blockIdx.x * 256 + threadIdx.x;    // x4 floats
    int elem = i << 2;
    int row = elem >> 10;
    int col = elem & 1023;
    const float* src = (row < 1536) ? (Wproj + (size_t)row * 1024 + col)
                                    : (Wphase + (size_t)(row - 1536) * 1024 + col);
    float4 v = *(const float4*)src;
    ushort4 h, l;
    bf16_split(v.x, h.x, l.x);
    bf16_split(v.y, h.y, l.y);
    bf16_split(v.z, h.z, l.z);
    bf16_split(v.w, h.w, l.w);
    ((ushort4*)WH)[i] = h;
    ((ushort4*)WL)[i] = l;
}

// ---------------------------------------------------------------------------
// pack_wres: W_res fp32 (1024 x 1022) -> WPH/WPL bf16 (1024 x 1024), padded 0
// ---------------------------------------------------------------------------
__global__ __launch_bounds__(256) void pack_wres_kernel(
    const float* __restrict__ Wres, unsigned short* __restrict__ WPH,
    unsigned short* __restrict__ WPL)
{
    int idx = blockIdx.x * 256 + threadIdx.x;   // 0 .. 1024*1024-1
    int d = idx >> 10;
    int j = idx & 1023;
    float v = (j < 1022) ? Wres[(size_t)d * 1022 + j] : 0.0f;
    unsigned short h, l;
    bf16_split(v, h, l);
    WPH[idx] = h;
    WPL[idx] = l;
}

// ---------------------------------------------------------------------------
// GEMM1 (split-bf16 MFMA): PT[j, r] = sum_d Wcat[j,d] * x[r,d] + bcat[j]
//   M = 1792 (j), N = 16384 (r), K = 1024.  3 MFMAs per hi/lo pair.
// LDS tiles in plane-major [kq][128 rows][8 bf16] layout: conflict-free
// ds_read_b128, and granule order matches global_load_lds lane order.
// ---------------------------------------------------------------------------
__global__ __launch_bounds__(256, 3) void gemm1_kernel(
    const unsigned short* __restrict__ WH, const unsigned short* __restrict__ WL,
    const unsigned short* __restrict__ XH, const unsigned short* __restrict__ XL,
    const float* __restrict__ bproj, const float* __restrict__ bphase,
    float* __restrict__ PT)
{
    __shared__ __attribute__((aligned(16))) unsigned short AH[4096];
    __shared__ __attribute__((aligned(16))) unsigned short AL[4096];
    __shared__ __attribute__((aligned(16))) unsigned short BH[4096];
    __shared__ __attribute__((aligned(16))) unsigned short BL[4096];

    const int tid  = threadIdx.x;
    const int lane = tid & 63;
    const int w    = tid >> 6;          // wave 0..3
    const int wm   = w >> 1, wn = w & 1;
    const int m0   = blockIdx.y * 128;  // j tile
    const int n0   = blockIdx.x * 128;  // r tile
    const int fr   = lane & 15;
    const int fq   = lane >> 4;         // 0..3

    f32x4 acc[4][4];
    #pragma unroll
    for (int i = 0; i < 4; i++)
        #pragma unroll
        for (int j = 0; j < 4; j++) acc[i][j] = (f32x4){0.f, 0.f, 0.f, 0.f};

    for (int kc = 0; kc < 32; kc++) {
        const int kbase = kc * 32;
        __syncthreads();
        #pragma unroll
        for (int t = 0; t < 2; t++) {
            int G  = w * 128 + t * 64 + lane;       // granule index 0..511
            int gm = G & 127;
            int gq = G >> 7;
            size_t offA = (size_t)(m0 + gm) * 1024 + kbase + gq * 8;
            size_t offB = (size_t)(n0 + gm) * 1024 + kbase + gq * 8;
            int ldsg = (w * 128 + t * 64) * 8;      // wave-uniform base (shorts)
            GL2LDS(WH + offA, &AH[ldsg]);
            GL2LDS(WL + offA, &AL[ldsg]);
            GL2LDS(XH + offB, &BH[ldsg]);
            GL2LDS(XL + offB, &BL[ldsg]);
        }
        __syncthreads();

        s16x8 ah[4], al[4], bh[4], bl[4];
        #pragma unroll
        for (int f = 0; f < 4; f++) {
            int aoff = (fq * 128 + wm * 64 + f * 16 + fr) * 8;
            int boff = (fq * 128 + wn * 64 + f * 16 + fr) * 8;
            ah[f] = *(const s16x8*)&AH[aoff];
            al[f] = *(const s16x8*)&AL[aoff];
            bh[f] = *(const s16x8*)&BH[boff];
            bl[f] = *(const s16x8*)&BL[boff];
        }
        #pragma unroll
        for (int i = 0; i < 4; i++)
            #pragma unroll
            for (int j = 0; j < 4; j++) {
                acc[i][j] = __builtin_amdgcn_mfma_f32_16x16x32_bf16(ah[i], bh[j], acc[i][j], 0, 0, 0);
                acc[i][j] = __builtin_amdgcn_mfma_f32_16x16x32_bf16(ah[i], bl[j], acc[i][j], 0, 0, 0);
                acc[i][j] = __builtin_amdgcn_mfma_f32_16x16x32_bf16(al[i], bh[j], acc[i][j], 0, 0, 0);
            }
    }

    // epilogue: C/D layout col = lane&15 (n=r), row = (lane>>4)*4+reg (m=j)
    #pragma unroll
    for (int i = 0; i < 4; i++) {
        int mbase = m0 + wm * 64 + i * 16 + fq * 4;
        #pragma unroll
        for (int j = 0; j < 4; j++) {
            int n = n0 + wn * 64 + j * 16 + fr;
            #pragma unroll
            for (int rg = 0; rg < 4; rg++) {
                int m = mbase + rg;
                float bias = (m < 1536) ? bproj[m] : bphase[m - 1536];
                PT[(size_t)m * NROW + n] = acc[i][j][rg] + bias;
            }
        }
    }
}

// ---------------------------------------------------------------------------
// Scan kernel: one block per (b, k) channel (unchanged from R1 except it only
// writes rho_re / rho_im / g back; rows 768+ become free for RTH/RTL).
// ---------------------------------------------------------------------------
__global__ __launch_bounds__(256) void scan_kernel(float* PT,
                                                   const float* lambda_ptr)
{
    const int bx = blockIdx.x;         // 0..1023
    const int k = bx & 255;
    const int b = bx >> 8;
    const int t = threadIdx.x;         // 0..255
    const size_t colb = (size_t)b * NSEQ;
    const size_t R = NROW;

    float* rowA  = PT + (size_t)(k)        * R + colb;  // a_raw -> rho_re
    float* rowW  = PT + (size_t)(256 + k)  * R + colb;  // w_raw -> rho_im
    float* rowP  = PT + (size_t)(512 + k)  * R + colb;  // p_raw -> g
    float* rowAl = PT + (size_t)(768 + k)  * R + colb;  // al_raw
    float* rowG  = PT + (size_t)(1024 + k) * R + colb;  // g_raw
    float* rowBe = PT + (size_t)(1280 + k) * R + colb;  // be_raw
    float* rowPq = PT + (size_t)(1536 + k) * R + colb;  // phase query

    __shared__ float s_al[NSEQ + 256];
    __shared__ float s_rr[NSEQ + 256];
    __shared__ float s_ri[NSEQ + 256];
    __shared__ float s_sa[256], s_sbr[256], s_sbi[256];

    const float lam = *lambda_ptr;

    for (int i = 0; i < 16; i++) {
        int n = i * 256 + t;
        float araw = rowA[n];
        float wraw = rowW[n];
        float praw = rowP[n];
        float alraw = rowAl[n];
        float A     = 3.0f * sigm(araw);
        float alpha = sigm(alraw);
        float omega = softplusf_(wraw);
        float ang   = fmaf(omega, log1pf((float)n), praw);
        float sn, cs;
        sincosf(ang, &sn, &cs);
        float amp = (1.0f - alpha) * A;
        int pidx = n + (n >> 4);
        s_al[pidx] = alpha;
        s_rr[pidx] = amp * cs;
        s_ri[pidx] = amp * sn;
    }
    __syncthreads();

    {
        float ap = 1.0f, br = 0.0f, bi = 0.0f;
        int base = t * 17;
        #pragma unroll
        for (int i = 0; i < 16; i++) {
            float a = s_al[base + i];
            br = fmaf(a, br, s_rr[base + i]);
            bi = fmaf(a, bi, s_ri[base + i]);
            ap *= a;
        }
        s_sa[t] = ap; s_sbr[t] = br; s_sbi[t] = bi;
    }
    __syncthreads();

    for (int off = 1; off < 256; off <<= 1) {
        float a2 = s_sa[t], b2r = s_sbr[t], b2i = s_sbi[t];
        float a1 = 1.0f, b1r = 0.0f, b1i = 0.0f;
        if (t >= off) { a1 = s_sa[t - off]; b1r = s_sbr[t - off]; b1i = s_sbi[t - off]; }
        __syncthreads();
        s_sa[t]  = a1 * a2;
        s_sbr[t] = fmaf(a2, b1r, b2r);
        s_sbi[t] = fmaf(a2, b1i, b2i);
        __syncthreads();
    }

    {
        float cr = 0.0f, ci = 0.0f;
        if (t > 0) { cr = s_sbr[t - 1]; ci = s_sbi[t - 1]; }
        int base = t * 17;
        #pragma unroll
        for (int i = 0; i < 16; i++) {
            float a = s_al[base + i];
            cr = fmaf(a, cr, s_rr[base + i]);
            ci = fmaf(a, ci, s_ri[base + i]);
            s_rr[base + i] = cr;
            s_ri[base + i] = ci;
        }
    }
    __syncthreads();

    for (int i = 0; i < 16; i++) {
        int n = i * 256 + t;
        float wraw = rowW[n];
        float praw = rowP[n];
        float beraw = rowBe[n];
        float graw = rowG[n];
        float pq = rowPq[n];

        float omega = softplusf_(wraw);
        float ang = fmaf(omega, log1pf((float)n), praw);
        float sn, cs;
        sincosf(ang, &sn, &cs);

        int pidx = n + (n >> 4);
        float rr = s_rr[pidx], ri = s_ri[pidx];
        float beta = sigm(beraw);
        float g = sigm(graw);

        float readout = rr * cs + ri * sn;
        rr -= beta * readout * cs;
        ri -= beta * readout * sn;

        float modulus = sqrtf(rr * rr + ri * ri + 1e-8f);
        float scale = fmaxf(modulus, 1.0f);
        rr /= scale; ri /= scale;

        float rho_re = rr * cs + ri * sn;
        float rho_im = -rr * sn + ri * cs;

        float rho_norm = sqrtf(rho_re * rho_re + rho_im * rho_im + 1e-8f);
        float sq, cq;
        sincosf(pq, &sq, &cq);
        float pa = (rho_re * cq + rho_im * sq) / rho_norm;
        float gate = sigm(lam * pa);
        rho_re *= gate;
        rho_im *= gate;

        rowA[n] = rho_re;
        rowW[n] = rho_im;
        rowP[n] = g;
    }
}

// ---------------------------------------------------------------------------
// pack_rho: fused cross-products + transpose + bf16 split.
// Reads PT rows 0..767 (rho_re, rho_im, g; coalesced), writes
// RTH/RTL bf16 [16384 r][1024 j] (j-contiguous for GEMM2), j>=1022 zero.
// ---------------------------------------------------------------------------
__global__ __launch_bounds__(256) void pack_rho_kernel(
    const float* __restrict__ PT, unsigned short* __restrict__ RTH,
    unsigned short* __restrict__ RTL)
{
    __shared__ float s_re[256 * 33];
    __shared__ float s_im[256 * 33];
    __shared__ float s_g [256 * 33];

    const int tid = threadIdx.x;
    const int r0 = blockIdx.x * 32;

    // load 3 chunks, coalesced (32 consecutive r per k-row)
    {
        int lr = tid & 31;
        int k0 = tid >> 5;       // 0..7
        for (int it = 0; it < 32; it++) {
            int k = it * 8 + k0;
            size_t go = (size_t)k * NROW + r0 + lr;
            s_re[k * 33 + lr] = PT[go];
            s_im[k * 33 + lr] = PT[(size_t)256 * NROW + go];
            s_g [k * 33 + lr] = PT[(size_t)512 * NROW + go];
        }
    }
    __syncthreads();

    const int r = tid >> 3;      // 0..31
    const int c = tid & 7;       // 0..7
    for (int i = 0; i < 16; i++) {
        int jb = (c + 8 * i) * 8;       // 0..1016, step 8
        unsigned short h[8], l[8];
        #pragma unroll
        for (int e = 0; e < 8; e++) {
            int j = jb + e;
            float v;
            if (j < 256) {
                v = s_g[j * 33 + r] * s_re[j * 33 + r];
            } else if (j < 512) {
                int k = j - 256;
                v = s_g[k * 33 + r] * s_im[k * 33 + r];
            } else if (j < 767) {
                int k = j - 512;
                float gc = 0.5f * (s_g[k * 33 + r] + s_g[(k + 1) * 33 + r]);
                v = gc * (s_re[k * 33 + r] * s_re[(k + 1) * 33 + r]
                        - s_im[k * 33 + r] * s_im[(k + 1) * 33 + r]);
            } else if (j < 1022) {
                int k = j - 767;
                float gc = 0.5f * (s_g[k * 33 + r] + s_g[(k + 1) * 33 + r]);
                v = gc * (s_re[k * 33 + r] * s_im[(k + 1) * 33 + r]
                        + s_im[k * 33 + r] * s_re[(k + 1) * 33 + r]);
            } else {
                v = 0.0f;
            }
            bf16_split(v, h[e], l[e]);
        }
        size_t off = (size_t)(r0 + r) * 1024 + jb;
        s16x8 hv, lv;
        #pragma unroll
        for (int e = 0; e < 8; e++) { hv[e] = (short)h[e]; lv[e] = (short)l[e]; }
        *(s16x8*)&RTH[off] = hv;
        *(s16x8*)&RTL[off] = lv;
    }
}

// ---------------------------------------------------------------------------
// GEMM2 (split-bf16 MFMA): out[r, d] = rs * sum_j RT[r,j] * WP[d,j]
//   M = 1024 (d), N = 16384 (r), K = 1024 (j).
// ---------------------------------------------------------------------------
__global__ __launch_bounds__(256, 3) void gemm2_kernel(
    const unsigned short* __restrict__ WPH, const unsigned short* __restrict__ WPL,
    const unsigned short* __restrict__ RTH, const unsigned short* __restrict__ RTL,
    const float* __restrict__ rs_ptr, float* __restrict__ out)
{
    __shared__ __attribute__((aligned(16))) unsigned short AH[4096];
    __shared__ __attribute__((aligned(16))) unsigned short AL[4096];
    __shared__ __attribute__((aligned(16))) unsigned short BH[4096];
    __shared__ __attribute__((aligned(16))) unsigned short BL[4096];

    const int tid  = threadIdx.x;
    const int lane = tid & 63;
    const int w    = tid >> 6;
    const int wm   = w >> 1, wn = w & 1;
    const int m0   = blockIdx.y * 128;  // d tile
    const int n0   = blockIdx.x * 128;  // r tile
    const int fr   = lane & 15;
    const int fq   = lane >> 4;
    const float rs = *rs_ptr;

    f32x4 acc[4][4];
    #pragma unroll
    for (int i = 0; i < 4; i++)
        #pragma unroll
        for (int j = 0; j < 4; j++) acc[i][j] = (f32x4){0.f, 0.f, 0.f, 0.f};

    for (int kc = 0; kc < 32; kc++) {
        const int kbase = kc * 32;
        __syncthreads();
        #pragma unroll
        for (int t = 0; t < 2; t++) {
            int G  = w * 128 + t * 64 + lane;
            int gm = G & 127;
            int gq = G >> 7;
            size_t offA = (size_t)(m0 + gm) * 1024 + kbase + gq * 8;
            size_t offB = (size_t)(n0 + gm) * 1024 + kbase + gq * 8;
            int ldsg = (w * 128 + t * 64) * 8;
            GL2LDS(WPH + offA, &AH[ldsg]);
            GL2LDS(WPL + offA, &AL[ldsg]);
            GL2LDS(RTH + offB, &BH[ldsg]);
            GL2LDS(RTL + offB, &BL[ldsg]);
        }
        __syncthreads();

        s16x8 ah[4], al[4], bh[4], bl[4];
        #pragma unroll
        for (int f = 0; f < 4; f++) {
            int aoff = (fq * 128 + wm * 64 + f * 16 + fr) * 8;
            int boff = (fq * 128 + wn * 64 + f * 16 + fr) * 8;
            ah[f] = *(const s16x8*)&AH[aoff];
            al[f] = *(const s16x8*)&AL[aoff];
            bh[f] = *(const s16x8*)&BH[boff];
            bl[f] = *(const s16x8*)&BL[boff];
        }
        #pragma unroll
        for (int i = 0; i < 4; i++)
            #pragma unroll
            for (int j = 0; j < 4; j++) {
                acc[i][j] = __builtin_amdgcn_mfma_f32_16x16x32_bf16(ah[i], bh[j], acc[i][j], 0, 0, 0);
                acc[i][j] = __builtin_amdgcn_mfma_f32_16x16x32_bf16(ah[i], bl[j], acc[i][j], 0, 0, 0);
                acc[i][j] = __builtin_amdgcn_mfma_f32_16x16x32_bf16(al[i], bh[j], acc[i][j], 0, 0, 0);
            }
    }

    // epilogue: col = n = r, row = m = d; 4 regs = 4 consecutive d -> float4
    #pragma unroll
    for (int i = 0; i < 4; i++) {
        int d = m0 + wm * 64 + i * 16 + fq * 4;
        #pragma unroll
        for (int j = 0; j < 4; j++) {
            int n = n0 + wn * 64 + j * 16 + fr;
            float4 v = { rs * acc[i][j][0], rs * acc[i][j][1],
                         rs * acc[i][j][2], rs * acc[i][j][3] };
            *(float4*)&out[(size_t)n * 1024 + d] = v;
        }
    }
}

// ---------------------------------------------------------------------------
extern "C" void kernel_launch(void* const* d_in, const int* in_sizes, int n_in,
                              void* d_out, int out_size, void* d_ws, size_t ws_size,
                              hipStream_t stream)
{
    const float* x      = (const float*)d_in[0];
    const float* Wproj  = (const float*)d_in[1];
    const float* bproj  = (const float*)d_in[2];
    const float* Wres   = (const float*)d_in[3];
    const float* Wphase = (const float*)d_in[4];
    const float* bphase = (const float*)d_in[5];
    const float* lam    = (const float*)d_in[6];
    const float* rs     = (const float*)d_in[7];
    float* out = (float*)d_out;

    // workspace layout (~124.8 MB):
    //   PT fp32 [1792][16384]           (117.4 MB)
    //   WH, WL bf16 [1792][1024]        (7.3 MB, after PT)
    // aliased into dead PT rows:
    //   RTH bf16 [16384][1024] = PT rows  768..1279
    //   RTL bf16 [16384][1024] = PT rows 1280..1791
    //   WPH/WPL bf16 [1024][1024] = PT rows 0..63 (after pack_rho)
    // d_out doubles as XH/XL bf16 scratch until gemm2 overwrites it.
    float* PT = (float*)d_ws;
    unsigned short* WH  = (unsigned short*)((char*)d_ws + (size_t)JTOT * NROW * 4);
    unsigned short* WL  = WH + (size_t)JTOT * 1024;
    unsigned short* RTH = (unsigned short*)(PT + (size_t)768 * NROW);
    unsigned short* RTL = RTH + (size_t)NROW * 1024;
    unsigned short* WPH = (unsigned short*)PT;
    unsigned short* WPL = WPH + (size_t)1024 * 1024;
    unsigned short* XH  = (unsigned short*)d_out;
    unsigned short* XL  = XH + (size_t)NROW * 1024;

    hipLaunchKernelGGL(split_x_kernel, dim3(NROW * D_MODEL / 1024), dim3(256), 0, stream,
                       x, XH, XL);
    hipLaunchKernelGGL(split_w_kernel, dim3(JTOT * D_MODEL / 1024), dim3(256), 0, stream,
                       Wproj, Wphase, WH, WL);
    hipLaunchKernelGGL(gemm1_kernel, dim3(NROW / 128, JTOT / 128), dim3(256), 0, stream,
                       WH, WL, XH, XL, bproj, bphase, PT);
    hipLaunchKernelGGL(scan_kernel, dim3(BATCH * KOSC), dim3(256), 0, stream,
                       PT, lam);
    hipLaunchKernelGGL(pack_rho_kernel, dim3(NROW / 32), dim3(256), 0, stream,
                       PT, RTH, RTL);
    hipLaunchKernelGGL(pack_wres_kernel, dim3(1024 * 1024 / 256), dim3(256), 0, stream,
                       Wres, WPH, WPL);
    hipLaunchKernelGGL(gemm2_kernel, dim3(NROW / 128, 1024 / 128), dim3(256), 0, stream,
                       WPH, WPL, RTH, RTL, rs, out);
}

// Round 3
// 535.077 us; speedup vs baseline: 2.4130x; 1.1954x over previous
//
#include <hip/hip_runtime.h>
#include <cmath>

// Problem constants
#define D_MODEL 1024
#define KOSC    256
#define NSEQ    4096
#define BATCH   4
#define NROW    (BATCH * NSEQ)   // 16384 rows (b*n)
#define JTOT    1792             // 6K proj + K phase

typedef short      s16x8 __attribute__((ext_vector_type(8)));
typedef float      f32x4 __attribute__((ext_vector_type(4)));

// async global->LDS, 16B per lane; LDS dest = wave-uniform base + lane*16
#define GL2LDS(gsrc, ldst)                                                      \
  __builtin_amdgcn_global_load_lds(                                             \
      (const __attribute__((address_space(1))) unsigned int*)(gsrc),            \
      (__attribute__((address_space(3))) unsigned int*)(ldst), 16, 0, 0)

__device__ __forceinline__ float sigm(float x) {
    return 1.0f / (1.0f + expf(-x));
}
__device__ __forceinline__ float softplusf_(float x) {
    return fmaxf(x, 0.0f) + log1pf(expf(-fabsf(x)));
}

// round-to-nearest-even bf16 split: f = hi + lo, residual ~2^-18 * |f|
__device__ __forceinline__ void bf16_split(float f, unsigned short& hi,
                                           unsigned short& lo) {
    unsigned u = __float_as_uint(f);
    unsigned r = u + 0x7FFFu + ((u >> 16) & 1u);
    hi = (unsigned short)(r >> 16);
    float fh = __uint_as_float((unsigned)hi << 16);
    float fl = f - fh;
    unsigned ul = __float_as_uint(fl);
    unsigned rl = ul + 0x7FFFu + ((ul >> 16) & 1u);
    lo = (unsigned short)(rl >> 16);
}

// ---------------------------------------------------------------------------
// split_x: x fp32 (16384x1024) -> XH, XL bf16 (in d_out scratch)
// ---------------------------------------------------------------------------
__global__ __launch_bounds__(256) void split_x_kernel(
    const float* __restrict__ x, unsigned short* __restrict__ XH,
    unsigned short* __restrict__ XL)
{
    int i = blockIdx.x * 256 + threadIdx.x;    // x4 floats
    float4 v = ((const float4*)x)[i];
    ushort4 h, l;
    bf16_split(v.x, h.x, l.x);
    bf16_split(v.y, h.y, l.y);
    bf16_split(v.z, h.z, l.z);
    bf16_split(v.w, h.w, l.w);
    ((ushort4*)XH)[i] = h;
    ((ushort4*)XL)[i] = l;
}

// ---------------------------------------------------------------------------
// split_w: [Wproj;Wphase] fp32 (1792x1024) -> WH, WL bf16
// ---------------------------------------------------------------------------
__global__ __launch_bounds__(256) void split_w_kernel(
    const float* __restrict__ Wproj, const float* __restrict__ Wphase,
    unsigned short* __restrict__ WH, unsigned short* __restrict__ WL)
{
    int i = blockIdx.x * 256 + threadIdx.x;    // x4 floats
    int elem = i << 2;
    int row = elem >> 10;
    int col = elem & 1023;
    const float* src = (row < 1536) ? (Wproj + (size_t)row * 1024 + col)
                                    : (Wphase + (size_t)(row - 1536) * 1024 + col);
    float4 v = *(const float4*)src;
    ushort4 h, l;
    bf16_split(v.x, h.x, l.x);
    bf16_split(v.y, h.y, l.y);
    bf16_split(v.z, h.z, l.z);
    bf16_split(v.w, h.w, l.w);
    ((ushort4*)WH)[i] = h;
    ((ushort4*)WL)[i] = l;
}

// ---------------------------------------------------------------------------
// pack_wres: W_res fp32 (1024 x 1022) -> WPH bf16 (1024 x 1024), padded 0
// (single bf16 on the W_res side; rho side keeps hi+lo)
// ---------------------------------------------------------------------------
__global__ __launch_bounds__(256) void pack_wres_kernel(
    const float* __restrict__ Wres, unsigned short* __restrict__ WPH)
{
    int idx = blockIdx.x * 256 + threadIdx.x;   // 0 .. 1024*1024-1
    int d = idx >> 10;
    int j = idx & 1023;
    float v = (j < 1022) ? Wres[(size_t)d * 1022 + j] : 0.0f;
    unsigned u = __float_as_uint(v);
    unsigned r = u + 0x7FFFu + ((u >> 16) & 1u);
    WPH[idx] = (unsigned short)(r >> 16);
}

// ---------------------------------------------------------------------------
// GEMM1-full (3-term split-bf16): PT rows 256..767 (omega, phi) — these feed
// the oscillator angle (amplified by log-position <= 8.3) and need ~fp32.
//   jt = blockIdx.y + 2
// ---------------------------------------------------------------------------
__global__ __launch_bounds__(256, 3) void gemm1_full_kernel(
    const unsigned short* __restrict__ WH, const unsigned short* __restrict__ WL,
    const unsigned short* __restrict__ XH, const unsigned short* __restrict__ XL,
    const float* __restrict__ bproj, float* __restrict__ PT)
{
    __shared__ __attribute__((aligned(16))) unsigned short AH[4096];
    __shared__ __attribute__((aligned(16))) unsigned short AL[4096];
    __shared__ __attribute__((aligned(16))) unsigned short BH[4096];
    __shared__ __attribute__((aligned(16))) unsigned short BL[4096];

    const int tid  = threadIdx.x;
    const int lane = tid & 63;
    const int w    = tid >> 6;          // wave 0..3
    const int wm   = w >> 1, wn = w & 1;
    const int m0   = (blockIdx.y + 2) * 128;  // j tile (rows 256..767)
    const int n0   = blockIdx.x * 128;        // r tile
    const int fr   = lane & 15;
    const int fq   = lane >> 4;         // 0..3

    f32x4 acc[4][4];
    #pragma unroll
    for (int i = 0; i < 4; i++)
        #pragma unroll
        for (int j = 0; j < 4; j++) acc[i][j] = (f32x4){0.f, 0.f, 0.f, 0.f};

    for (int kc = 0; kc < 32; kc++) {
        const int kbase = kc * 32;
        __syncthreads();
        #pragma unroll
        for (int t = 0; t < 2; t++) {
            int G  = w * 128 + t * 64 + lane;       // granule index 0..511
            int gm = G & 127;
            int gq = G >> 7;
            size_t offA = (size_t)(m0 + gm) * 1024 + kbase + gq * 8;
            size_t offB = (size_t)(n0 + gm) * 1024 + kbase + gq * 8;
            int ldsg = (w * 128 + t * 64) * 8;      // wave-uniform base (shorts)
            GL2LDS(WH + offA, &AH[ldsg]);
            GL2LDS(WL + offA, &AL[ldsg]);
            GL2LDS(XH + offB, &BH[ldsg]);
            GL2LDS(XL + offB, &BL[ldsg]);
        }
        __syncthreads();

        s16x8 ah[4], al[4], bh[4], bl[4];
        #pragma unroll
        for (int f = 0; f < 4; f++) {
            int aoff = (fq * 128 + wm * 64 + f * 16 + fr) * 8;
            int boff = (fq * 128 + wn * 64 + f * 16 + fr) * 8;
            ah[f] = *(const s16x8*)&AH[aoff];
            al[f] = *(const s16x8*)&AL[aoff];
            bh[f] = *(const s16x8*)&BH[boff];
            bl[f] = *(const s16x8*)&BL[boff];
        }
        #pragma unroll
        for (int i = 0; i < 4; i++)
            #pragma unroll
            for (int j = 0; j < 4; j++) {
                acc[i][j] = __builtin_amdgcn_mfma_f32_16x16x32_bf16(ah[i], bh[j], acc[i][j], 0, 0, 0);
                acc[i][j] = __builtin_amdgcn_mfma_f32_16x16x32_bf16(ah[i], bl[j], acc[i][j], 0, 0, 0);
                acc[i][j] = __builtin_amdgcn_mfma_f32_16x16x32_bf16(al[i], bh[j], acc[i][j], 0, 0, 0);
            }
    }

    #pragma unroll
    for (int i = 0; i < 4; i++) {
        int mbase = m0 + wm * 64 + i * 16 + fq * 4;
        #pragma unroll
        for (int j = 0; j < 4; j++) {
            int n = n0 + wn * 64 + j * 16 + fr;
            #pragma unroll
            for (int rg = 0; rg < 4; rg++) {
                int m = mbase + rg;
                PT[(size_t)m * NROW + n] = acc[i][j][rg] + bproj[m];
            }
        }
    }
}

// ---------------------------------------------------------------------------
// GEMM1-lite (single bf16): PT rows 0..255, 768..1791 (A, alpha, g, beta, pq).
// These pass through sigmoids (gain <= 0.75) and reach the output attenuated
// by res_scale*||W_res row|| ~ 3e-3 — bf16 precision is ample.
//   jt = (blockIdx.y < 2) ? blockIdx.y : blockIdx.y + 4
// ---------------------------------------------------------------------------
__global__ __launch_bounds__(256, 4) void gemm1_lite_kernel(
    const unsigned short* __restrict__ WH, const unsigned short* __restrict__ XH,
    const float* __restrict__ bproj, const float* __restrict__ bphase,
    float* __restrict__ PT)
{
    __shared__ __attribute__((aligned(16))) unsigned short AH[4096];
    __shared__ __attribute__((aligned(16))) unsigned short BH[4096];

    const int tid  = threadIdx.x;
    const int lane = tid & 63;
    const int w    = tid >> 6;
    const int wm   = w >> 1, wn = w & 1;
    const int yt   = blockIdx.y;
    const int jt   = (yt < 2) ? yt : yt + 4;
    const int m0   = jt * 128;
    const int n0   = blockIdx.x * 128;
    const int fr   = lane & 15;
    const int fq   = lane >> 4;

    f32x4 acc[4][4];
    #pragma unroll
    for (int i = 0; i < 4; i++)
        #pragma unroll
        for (int j = 0; j < 4; j++) acc[i][j] = (f32x4){0.f, 0.f, 0.f, 0.f};

    for (int kc = 0; kc < 32; kc++) {
        const int kbase = kc * 32;
        __syncthreads();
        #pragma unroll
        for (int t = 0; t < 2; t++) {
            int G  = w * 128 + t * 64 + lane;
            int gm = G & 127;
            int gq = G >> 7;
            size_t offA = (size_t)(m0 + gm) * 1024 + kbase + gq * 8;
            size_t offB = (size_t)(n0 + gm) * 1024 + kbase + gq * 8;
            int ldsg = (w * 128 + t * 64) * 8;
            GL2LDS(WH + offA, &AH[ldsg]);
            GL2LDS(XH + offB, &BH[ldsg]);
        }
        __syncthreads();

        s16x8 ah[4], bh[4];
        #pragma unroll
        for (int f = 0; f < 4; f++) {
            int aoff = (fq * 128 + wm * 64 + f * 16 + fr) * 8;
            int boff = (fq * 128 + wn * 64 + f * 16 + fr) * 8;
            ah[f] = *(const s16x8*)&AH[aoff];
            bh[f] = *(const s16x8*)&BH[boff];
        }
        #pragma unroll
        for (int i = 0; i < 4; i++)
            #pragma unroll
            for (int j = 0; j < 4; j++)
                acc[i][j] = __builtin_amdgcn_mfma_f32_16x16x32_bf16(ah[i], bh[j], acc[i][j], 0, 0, 0);
    }

    #pragma unroll
    for (int i = 0; i < 4; i++) {
        int mbase = m0 + wm * 64 + i * 16 + fq * 4;
        #pragma unroll
        for (int j = 0; j < 4; j++) {
            int n = n0 + wn * 64 + j * 16 + fr;
            #pragma unroll
            for (int rg = 0; rg < 4; rg++) {
                int m = mbase + rg;
                float bias = (m < 1536) ? bproj[m] : bphase[m - 1536];
                PT[(size_t)m * NROW + n] = acc[i][j][rg] + bias;
            }
        }
    }
}

// ---------------------------------------------------------------------------
// Scan kernel: one block per (b, k) channel.
// ---------------------------------------------------------------------------
__global__ __launch_bounds__(256) void scan_kernel(float* PT,
                                                   const float* lambda_ptr)
{
    const int bx = blockIdx.x;         // 0..1023
    const int k = bx & 255;
    const int b = bx >> 8;
    const int t = threadIdx.x;         // 0..255
    const size_t colb = (size_t)b * NSEQ;
    const size_t R = NROW;

    float* rowA  = PT + (size_t)(k)        * R + colb;  // a_raw -> rho_re
    float* rowW  = PT + (size_t)(256 + k)  * R + colb;  // w_raw -> rho_im
    float* rowP  = PT + (size_t)(512 + k)  * R + colb;  // p_raw -> g
    float* rowAl = PT + (size_t)(768 + k)  * R + colb;  // al_raw
    float* rowG  = PT + (size_t)(1024 + k) * R + colb;  // g_raw
    float* rowBe = PT + (size_t)(1280 + k) * R + colb;  // be_raw
    float* rowPq = PT + (size_t)(1536 + k) * R + colb;  // phase query

    __shared__ float s_al[NSEQ + 256];
    __shared__ float s_rr[NSEQ + 256];
    __shared__ float s_ri[NSEQ + 256];
    __shared__ float s_sa[256], s_sbr[256], s_sbi[256];

    const float lam = *lambda_ptr;

    for (int i = 0; i < 16; i++) {
        int n = i * 256 + t;
        float araw = rowA[n];
        float wraw = rowW[n];
        float praw = rowP[n];
        float alraw = rowAl[n];
        float A     = 3.0f * sigm(araw);
        float alpha = sigm(alraw);
        float omega = softplusf_(wraw);
        float ang   = fmaf(omega, log1pf((float)n), praw);
        float sn, cs;
        sincosf(ang, &sn, &cs);
        float amp = (1.0f - alpha) * A;
        int pidx = n + (n >> 4);
        s_al[pidx] = alpha;
        s_rr[pidx] = amp * cs;
        s_ri[pidx] = amp * sn;
    }
    __syncthreads();

    {
        float ap = 1.0f, br = 0.0f, bi = 0.0f;
        int base = t * 17;
        #pragma unroll
        for (int i = 0; i < 16; i++) {
            float a = s_al[base + i];
            br = fmaf(a, br, s_rr[base + i]);
            bi = fmaf(a, bi, s_ri[base + i]);
            ap *= a;
        }
        s_sa[t] = ap; s_sbr[t] = br; s_sbi[t] = bi;
    }
    __syncthreads();

    for (int off = 1; off < 256; off <<= 1) {
        float a2 = s_sa[t], b2r = s_sbr[t], b2i = s_sbi[t];
        float a1 = 1.0f, b1r = 0.0f, b1i = 0.0f;
        if (t >= off) { a1 = s_sa[t - off]; b1r = s_sbr[t - off]; b1i = s_sbi[t - off]; }
        __syncthreads();
        s_sa[t]  = a1 * a2;
        s_sbr[t] = fmaf(a2, b1r, b2r);
        s_sbi[t] = fmaf(a2, b1i, b2i);
        __syncthreads();
    }

    {
        float cr = 0.0f, ci = 0.0f;
        if (t > 0) { cr = s_sbr[t - 1]; ci = s_sbi[t - 1]; }
        int base = t * 17;
        #pragma unroll
        for (int i = 0; i < 16; i++) {
            float a = s_al[base + i];
            cr = fmaf(a, cr, s_rr[base + i]);
            ci = fmaf(a, ci, s_ri[base + i]);
            s_rr[base + i] = cr;
            s_ri[base + i] = ci;
        }
    }
    __syncthreads();

    for (int i = 0; i < 16; i++) {
        int n = i * 256 + t;
        float wraw = rowW[n];
        float praw = rowP[n];
        float beraw = rowBe[n];
        float graw = rowG[n];
        float pq = rowPq[n];

        float omega = softplusf_(wraw);
        float ang = fmaf(omega, log1pf((float)n), praw);
        float sn, cs;
        sincosf(ang, &sn, &cs);

        int pidx = n + (n >> 4);
        float rr = s_rr[pidx], ri = s_ri[pidx];
        float beta = sigm(beraw);
        float g = sigm(graw);

        float readout = rr * cs + ri * sn;
        rr -= beta * readout * cs;
        ri -= beta * readout * sn;

        float modulus = sqrtf(rr * rr + ri * ri + 1e-8f);
        float scale = fmaxf(modulus, 1.0f);
        rr /= scale; ri /= scale;

        float rho_re = rr * cs + ri * sn;
        float rho_im = -rr * sn + ri * cs;

        float rho_norm = sqrtf(rho_re * rho_re + rho_im * rho_im + 1e-8f);
        float sq, cq;
        sincosf(pq, &sq, &cq);
        float pa = (rho_re * cq + rho_im * sq) / rho_norm;
        float gate = sigm(lam * pa);
        rho_re *= gate;
        rho_im *= gate;

        rowA[n] = rho_re;
        rowW[n] = rho_im;
        rowP[n] = g;
    }
}

// ---------------------------------------------------------------------------
// pack_rho: fused cross-products + transpose + bf16 split.
// ---------------------------------------------------------------------------
__global__ __launch_bounds__(256) void pack_rho_kernel(
    const float* __restrict__ PT, unsigned short* __restrict__ RTH,
    unsigned short* __restrict__ RTL)
{
    __shared__ float s_re[256 * 33];
    __shared__ float s_im[256 * 33];
    __shared__ float s_g [256 * 33];

    const int tid = threadIdx.x;
    const int r0 = blockIdx.x * 32;

    {
        int lr = tid & 31;
        int k0 = tid >> 5;       // 0..7
        for (int it = 0; it < 32; it++) {
            int k = it * 8 + k0;
            size_t go = (size_t)k * NROW + r0 + lr;
            s_re[k * 33 + lr] = PT[go];
            s_im[k * 33 + lr] = PT[(size_t)256 * NROW + go];
            s_g [k * 33 + lr] = PT[(size_t)512 * NROW + go];
        }
    }
    __syncthreads();

    const int r = tid >> 3;      // 0..31
    const int c = tid & 7;       // 0..7
    for (int i = 0; i < 16; i++) {
        int jb = (c + 8 * i) * 8;       // 0..1016, step 8
        unsigned short h[8], l[8];
        #pragma unroll
        for (int e = 0; e < 8; e++) {
            int j = jb + e;
            float v;
            if (j < 256) {
                v = s_g[j * 33 + r] * s_re[j * 33 + r];
            } else if (j < 512) {
                int k = j - 256;
                v = s_g[k * 33 + r] * s_im[k * 33 + r];
            } else if (j < 767) {
                int k = j - 512;
                float gc = 0.5f * (s_g[k * 33 + r] + s_g[(k + 1) * 33 + r]);
                v = gc * (s_re[k * 33 + r] * s_re[(k + 1) * 33 + r]
                        - s_im[k * 33 + r] * s_im[(k + 1) * 33 + r]);
            } else if (j < 1022) {
                int k = j - 767;
                float gc = 0.5f * (s_g[k * 33 + r] + s_g[(k + 1) * 33 + r]);
                v = gc * (s_re[k * 33 + r] * s_im[(k + 1) * 33 + r]
                        + s_im[k * 33 + r] * s_re[(k + 1) * 33 + r]);
            } else {
                v = 0.0f;
            }
            bf16_split(v, h[e], l[e]);
        }
        size_t off = (size_t)(r0 + r) * 1024 + jb;
        s16x8 hv, lv;
        #pragma unroll
        for (int e = 0; e < 8; e++) { hv[e] = (short)h[e]; lv[e] = (short)l[e]; }
        *(s16x8*)&RTH[off] = hv;
        *(s16x8*)&RTL[off] = lv;
    }
}

// ---------------------------------------------------------------------------
// GEMM2 (2-term: W_res bf16, rho hi+lo): out[r,d] = rs * sum_j RT[r,j]*WP[d,j]
// ---------------------------------------------------------------------------
__global__ __launch_bounds__(256, 3) void gemm2_kernel(
    const unsigned short* __restrict__ WPH,
    const unsigned short* __restrict__ RTH, const unsigned short* __restrict__ RTL,
    const float* __restrict__ rs_ptr, float* __restrict__ out)
{
    __shared__ __attribute__((aligned(16))) unsigned short AH[4096];
    __shared__ __attribute__((aligned(16))) unsigned short BH[4096];
    __shared__ __attribute__((aligned(16))) unsigned short BL[4096];

    const int tid  = threadIdx.x;
    const int lane = tid & 63;
    const int w    = tid >> 6;
    const int wm   = w >> 1, wn = w & 1;
    const int m0   = blockIdx.y * 128;  // d tile
    const int n0   = blockIdx.x * 128;  // r tile
    const int fr   = lane & 15;
    const int fq   = lane >> 4;
    const float rs = *rs_ptr;

    f32x4 acc[4][4];
    #pragma unroll
    for (int i = 0; i < 4; i++)
        #pragma unroll
        for (int j = 0; j < 4; j++) acc[i][j] = (f32x4){0.f, 0.f, 0.f, 0.f};

    for (int kc = 0; kc < 32; kc++) {
        const int kbase = kc * 32;
        __syncthreads();
        #pragma unroll
        for (int t = 0; t < 2; t++) {
            int G  = w * 128 + t * 64 + lane;
            int gm = G & 127;
            int gq = G >> 7;
            size_t offA = (size_t)(m0 + gm) * 1024 + kbase + gq * 8;
            size_t offB = (size_t)(n0 + gm) * 1024 + kbase + gq * 8;
            int ldsg = (w * 128 + t * 64) * 8;
            GL2LDS(WPH + offA, &AH[ldsg]);
            GL2LDS(RTH + offB, &BH[ldsg]);
            GL2LDS(RTL + offB, &BL[ldsg]);
        }
        __syncthreads();

        s16x8 ah[4], bh[4], bl[4];
        #pragma unroll
        for (int f = 0; f < 4; f++) {
            int aoff = (fq * 128 + wm * 64 + f * 16 + fr) * 8;
            int boff = (fq * 128 + wn * 64 + f * 16 + fr) * 8;
            ah[f] = *(const s16x8*)&AH[aoff];
            bh[f] = *(const s16x8*)&BH[boff];
            bl[f] = *(const s16x8*)&BL[boff];
        }
        #pragma unroll
        for (int i = 0; i < 4; i++)
            #pragma unroll
            for (int j = 0; j < 4; j++) {
                acc[i][j] = __builtin_amdgcn_mfma_f32_16x16x32_bf16(ah[i], bh[j], acc[i][j], 0, 0, 0);
                acc[i][j] = __builtin_amdgcn_mfma_f32_16x16x32_bf16(ah[i], bl[j], acc[i][j], 0, 0, 0);
            }
    }

    #pragma unroll
    for (int i = 0; i < 4; i++) {
        int d = m0 + wm * 64 + i * 16 + fq * 4;
        #pragma unroll
        for (int j = 0; j < 4; j++) {
            int n = n0 + wn * 64 + j * 16 + fr;
            float4 v = { rs * acc[i][j][0], rs * acc[i][j][1],
                         rs * acc[i][j][2], rs * acc[i][j][3] };
            *(float4*)&out[(size_t)n * 1024 + d] = v;
        }
    }
}

// ---------------------------------------------------------------------------
extern "C" void kernel_launch(void* const* d_in, const int* in_sizes, int n_in,
                              void* d_out, int out_size, void* d_ws, size_t ws_size,
                              hipStream_t stream)
{
    const float* x      = (const float*)d_in[0];
    const float* Wproj  = (const float*)d_in[1];
    const float* bproj  = (const float*)d_in[2];
    const float* Wres   = (const float*)d_in[3];
    const float* Wphase = (const float*)d_in[4];
    const float* bphase = (const float*)d_in[5];
    const float* lam    = (const float*)d_in[6];
    const float* rs     = (const float*)d_in[7];
    float* out = (float*)d_out;

    // workspace layout (~124.8 MB):
    //   PT fp32 [1792][16384]           (117.4 MB)
    //   WH, WL bf16 [1792][1024]        (7.3 MB, after PT)
    // aliased into dead PT rows:
    //   RTH bf16 [16384][1024] = PT rows  768..1279
    //   RTL bf16 [16384][1024] = PT rows 1280..1791
    //   WPH bf16 [1024][1024]  = PT rows 0..31 (after pack_rho)
    // d_out doubles as XH/XL bf16 scratch until gemm2 overwrites it.
    float* PT = (float*)d_ws;
    unsigned short* WH  = (unsigned short*)((char*)d_ws + (size_t)JTOT * NROW * 4);
    unsigned short* WL  = WH + (size_t)JTOT * 1024;
    unsigned short* RTH = (unsigned short*)(PT + (size_t)768 * NROW);
    unsigned short* RTL = RTH + (size_t)NROW * 1024;
    unsigned short* WPH = (unsigned short*)PT;
    unsigned short* XH  = (unsigned short*)d_out;
    unsigned short* XL  = XH + (size_t)NROW * 1024;

    hipLaunchKernelGGL(split_x_kernel, dim3(NROW * D_MODEL / 1024), dim3(256), 0, stream,
                       x, XH, XL);
    hipLaunchKernelGGL(split_w_kernel, dim3(JTOT * D_MODEL / 1024), dim3(256), 0, stream,
                       Wproj, Wphase, WH, WL);
    hipLaunchKernelGGL(gemm1_full_kernel, dim3(NROW / 128, 4), dim3(256), 0, stream,
                       WH, WL, XH, XL, bproj, PT);
    hipLaunchKernelGGL(gemm1_lite_kernel, dim3(NROW / 128, 10), dim3(256), 0, stream,
                       WH, XH, bproj, bphase, PT);
    hipLaunchKernelGGL(scan_kernel, dim3(BATCH * KOSC), dim3(256), 0, stream,
                       PT, lam);
    hipLaunchKernelGGL(pack_rho_kernel, dim3(NROW / 32), dim3(256), 0, stream,
                       PT, RTH, RTL);
    hipLaunchKernelGGL(pack_wres_kernel, dim3(1024 * 1024 / 256), dim3(256), 0, stream,
                       Wres, WPH);
    hipLaunchKernelGGL(gemm2_kernel, dim3(NROW / 128, 1024 / 128), dim3(256), 0, stream,
                       WPH, RTH, RTL, rs, out);
}